// Round 9
// baseline (447.244 us; speedup 1.0000x reference)
//
#include <hip/hip_runtime.h>
#include <stdint.h>

// Problem constants: x [B=2, S=4096, K=4096] -> M = 8192; weight [N=4096, K=4096]
#define M_DIM 8192
#define N_DIM 4096
#define K_DIM 4096

using int4v = __attribute__((ext_vector_type(4))) int;

// ---------------------------------------------------------------------------
// Pack kernel: int32 (widened int8 in [-127,127]) -> int8 bytes.
// ---------------------------------------------------------------------------
__global__ __launch_bounds__(256) void pack_kernel(const int4* __restrict__ sx,
                                                   const int4* __restrict__ sw,
                                                   unsigned int* __restrict__ dst,
                                                   int nx, int ntot) {
    int idx = blockIdx.x * blockDim.x + threadIdx.x;
    if (idx >= ntot) return;
    int4 v = (idx < nx) ? sx[idx] : sw[idx - nx];
    dst[idx] = (v.x & 0xff) | ((v.y & 0xff) << 8) | ((v.z & 0xff) << 16) |
               ((v.w & 0xff) << 24);
}

// ---------------------------------------------------------------------------
// Async global -> LDS copy, 16 B per lane (global_load_lds_dwordx4).
// ---------------------------------------------------------------------------
__device__ __forceinline__ void async_copy16(const char* g, char* l) {
    __builtin_amdgcn_global_load_lds(
        (const __attribute__((address_space(1))) char*)g,
        (__attribute__((address_space(3))) char*)l, 16, 0, 0);
}

// ---------------------------------------------------------------------------
// 256x256 i8 GEMM: A via LDS, B streamed global->VGPR (flatmm style) (r9).
// R0-R8 post-mortem: 8 schedule variants all == serial sum of MFMA pipe
// (2612 cyc) + LDS pipe (~2800 cyc) per K-tile: the single per-CU LDS pipe
// serves all 8 waves' read bursts round-robin, so no intra-CU schedule can
// overlap the pipes. Fix: REMOVE traffic from the LDS pipe. B fragments are
// register-shaped (16 B/lane) and B panels are L2-resident under the square
// XCD chunks -> load B directly global->VGPR on the vmem pipe (a separate
// resource), keep only A staged through LDS.
//   LDS/tile: A-writes 32 KB + A-reads 131 KB (~1800 cyc) vs old 196+64 KB.
//   vmem/tile: B 64 KB from L2 (~1150 cyc, overlaps LDS & MFMA).
//   Worst case (still-serial LDS+MFMA): 4400 cyc/tile vs r2's 5475.
// Counted vmcnt, never 0 in main loop: top vmcnt(4) completes A(t)+B.ks0(t)
// (issued a full body ago), mid-body vmcnt(8) completes B.ks1(t) (issued
// half a body ago). One barrier per tile (safe: every ds_read is consumed
// by an MFMA before the barrier; staging writes to the other buffer).
//
// 512 thr = 8 waves (2M x 4N), wave tile 128x64 (8x4 of 16x16x64 MFMA),
// BK=128B. LDS: 2 x A 32 KiB = 64 KiB. VGPR: br 32 + a 32 + addr (~100)
// + acc 128 AGPR -> 2 waves/SIMD.
//
// LDS swizzle for A (verified, 0 conflicts): 16-B chunk (row, cg) stored at
// cg ^ ((row>>1)&7); global source pre-swizzled, reads XOR-correct.
// ---------------------------------------------------------------------------
__global__ __launch_bounds__(512, 2) void gemm_i8_kernel(
    const char* __restrict__ Aq,   // [M, K] int8
    const char* __restrict__ Bq,   // [N, K] int8
    const int* __restrict__ bias,  // [N] int32 (widened int8)
    const float* __restrict__ a_ptr,
    const float* __restrict__ b_ptr,
    int32_t* __restrict__ out)     // [M, N] int32 holding int8 values
{
    __shared__ char As0[256 * 128];   // 32 KiB each
    __shared__ char As1[256 * 128];

    const int tid  = threadIdx.x;
    const int lane = tid & 63;
    const int wave = tid >> 6;
    const int wr   = wave >> 2;   // 0..1 -> 128 M-rows
    const int wc   = wave & 3;    // 0..3 -> 64 N-cols

    // Square XCD chunks (measured FETCH ~99 MB): 512 blocks = 8 XCDs x 64;
    // per XCD 8 M-tiles x 8 N-tiles -> A 8 MB + B 8 MB footprint (L2-hot).
    const int bid = blockIdx.x;
    const int xcd = bid & 7;
    const int lin = bid >> 3;                       // 0..63
    const int tile_m = (xcd & 3) * 8 + (lin & 7);   // 0..31
    const int tile_n = (xcd >> 2) * 8 + (lin >> 3); // 0..15
    const int m0 = tile_m * 256;
    const int n0 = tile_n * 256;

    const float alpha = *a_ptr;
    const float beta  = *b_ptr;

    int4v acc[8][4] = {};   // 128 accumulator regs (AGPR)
    int4v br[8];            // B fragments, [j*2 + ks]

    // Fragment coords: lane holds op row m/n = lane&15, k-group = lane>>4.
    const int fr = lane & 15;
    const int gw = lane >> 4;
    const int swz = (fr >> 1) & 7;
    const int k0off = (gw ^ swz) << 4;          // A k-substep 0 (swizzled)
    const int k1off = ((4 + gw) ^ swz) << 4;    // A k-substep 1
    const int arow = wr * 128 + fr;

    // B direct-from-global per-lane base: row n0+wc*64+fr, k byte gw*16.
    const char* gBf = Bq + (size_t)(n0 + wc * 64 + fr) * K_DIM + gw * 16;

    // A staging (verified r2/r6/r7): thread t covers 4 chunks; global
    // cg = (t&7) ^ ((t>>4)&7) pre-applies the storage swizzle.
    const int srow = tid >> 3;                               // 0..63
    const int scg  = ((tid & 7) ^ ((tid >> 4) & 7)) << 4;    // byte col offset
    const char* gA0 = Aq + (size_t)(m0 + srow) * K_DIM + scg;
    const char* gA1 = gA0 + (size_t)64 * K_DIM;

#define STAGE_A_TILE(AS, t)                                                  \
    {                                                                        \
        const size_t offL = (size_t)(t) * 128;                               \
        const size_t offH = (size_t)128 * K_DIM + (size_t)(t) * 128;         \
        async_copy16(gA0 + offL, &AS[(tid << 4)]);                           \
        async_copy16(gA1 + offL, &AS[(tid << 4) + 8192]);                    \
        async_copy16(gA0 + offH, &AS[16384 + (tid << 4)]);                   \
        async_copy16(gA1 + offH, &AS[16384 + (tid << 4) + 8192]);            \
    }

#define LOAD_B_KS(t, ks)                                                     \
    {                                                                        \
        _Pragma("unroll") for (int j = 0; j < 4; ++j)                        \
            br[j * 2 + (ks)] = *(const int4v*)(                              \
                gBf + (size_t)(j * 16) * K_DIM + (size_t)(t) * 128 +         \
                (ks) * 64);                                                  \
        __builtin_amdgcn_sched_barrier(0);                                   \
    }

    // 8 ds_read_b128 + 32 MFMA for one k-substep; compiler counted-lgkm.
#define COMPUTE_KS(AS, ks, ko)                                               \
    {                                                                        \
        int4v a[8];                                                          \
        _Pragma("unroll") for (int i = 0; i < 8; ++i)                        \
            a[i] = *(const int4v*)&AS[(arow + i * 16) * 128 + (ko)];         \
        __builtin_amdgcn_s_setprio(1);                                       \
        _Pragma("unroll") for (int i = 0; i < 8; ++i)                        \
        _Pragma("unroll") for (int j = 0; j < 4; ++j)                        \
            acc[i][j] = __builtin_amdgcn_mfma_i32_16x16x64_i8(               \
                a[i], br[j * 2 + (ks)], acc[i][j], 0, 0, 0);                 \
        __builtin_amdgcn_s_setprio(0);                                       \
    }

    // One tile: top wait completes A(t)+B.ks0(t) (leaves B.ks1(t) flying),
    // barrier; stage A(t+1); ks0 compute; reload B.ks0(t+1); mid wait
    // completes B.ks1(t); ks1 compute; reload B.ks1(t+1).
#define BODY(CUR, NXT, t)                                                    \
    {                                                                        \
        asm volatile("s_waitcnt vmcnt(4)" ::: "memory");                     \
        __builtin_amdgcn_s_barrier();                                        \
        __builtin_amdgcn_sched_barrier(0);                                   \
        STAGE_A_TILE(NXT, (t) + 1);                                          \
        __builtin_amdgcn_sched_barrier(0);                                   \
        COMPUTE_KS(CUR, 0, k0off);                                           \
        LOAD_B_KS((t) + 1, 0);                                               \
        asm volatile("s_waitcnt vmcnt(8)" ::: "memory");                     \
        __builtin_amdgcn_sched_barrier(0);                                   \
        COMPUTE_KS(CUR, 1, k1off);                                           \
        LOAD_B_KS((t) + 1, 1);                                               \
    }

    // Prologue: A(0) + B(0) in flight (same FIFO shape as steady state).
    STAGE_A_TILE(As0, 0);
    LOAD_B_KS(0, 0);
    LOAD_B_KS(0, 1);

#pragma unroll 1
    for (int i = 0; i < 15; ++i) {
        BODY(As0, As1, 2 * i);
        BODY(As1, As0, 2 * i + 1);
    }
    // Tile 30 (buf0): stages A(31) -> buf1, loads B(31).
    BODY(As0, As1, 30);
    // Tile 31 (buf1): no staging, no B reload; drain B.ks1(31) mid-body.
    {
        asm volatile("s_waitcnt vmcnt(4)" ::: "memory");
        __builtin_amdgcn_s_barrier();
        __builtin_amdgcn_sched_barrier(0);
        COMPUTE_KS(As1, 0, k0off);
        asm volatile("s_waitcnt vmcnt(0)" ::: "memory");
        __builtin_amdgcn_sched_barrier(0);
        COMPUTE_KS(As1, 1, k1off);
    }

    // Epilogue: C/D layout col = lane&15, row = (lane>>4)*4 + reg.
    const int orow = (lane >> 4) * 4;
    const int ocol = lane & 15;
#pragma unroll
    for (int j = 0; j < 4; ++j) {
        const int gn = n0 + wc * 64 + j * 16 + ocol;
        const float bb = beta * (float)bias[gn];
#pragma unroll
        for (int i = 0; i < 8; ++i) {
            const int gm = m0 + wr * 128 + i * 16 + orow;
#pragma unroll
            for (int r = 0; r < 4; ++r) {
                float v = alpha * (float)acc[i][j][r] + bb;
                v = rintf(v);                       // round half-to-even (numpy)
                v = fminf(fmaxf(v, -128.0f), 127.0f);
                out[(size_t)(gm + r) * N_DIM + gn] = (int32_t)v;
            }
        }
    }
}

// ---------------------------------------------------------------------------
extern "C" void kernel_launch(void* const* d_in, const int* in_sizes, int n_in,
                              void* d_out, int out_size, void* d_ws, size_t ws_size,
                              hipStream_t stream) {
    const int*   x    = (const int*)d_in[0];    // [M, K] widened int8
    const int*   w    = (const int*)d_in[1];    // [N, K] widened int8
    const int*   bias = (const int*)d_in[2];    // [N]
    const float* a    = (const float*)d_in[3];  // alpha scalar
    const float* b    = (const float*)d_in[4];  // beta scalar
    int32_t*     out  = (int32_t*)d_out;        // [M, N]

    char* xq = (char*)d_ws;                     // 32 MiB packed x
    const int nx   = (M_DIM * K_DIM) / 4;       // int4-groups in x
    const int nw   = (N_DIM * K_DIM) / 4;
    const int ntot = nx + nw;
    pack_kernel<<<(ntot + 255) / 256, 256, 0, stream>>>(
        (const int4*)x, (const int4*)w, (unsigned int*)xq, nx, ntot);

    char* wq = xq + (size_t)M_DIM * K_DIM;      // 16 MiB packed weight

    dim3 grid((M_DIM / 256) * (N_DIM / 256));   // 512 blocks, 1D for XCD swizzle
    gemm_i8_kernel<<<grid, 512, 0, stream>>>(xq, wq, bias, a, b, out);
}